// Round 10
// baseline (246.773 us; speedup 1.0000x reference)
//
#include <hip/hip_runtime.h>
#include <stdint.h>

// out[b,n] = sum_{c,hw} x[b,c,hw]*W_s[n,hw]*W_d[n,c] + W_b[n]
// GEMM: A = x (M=8192, K=3136), B = W_s (N=1024, K=3136), fused c-contraction.
// R9: R5 core (256x128, 8 waves, BK=64, split-K x2, 2 blocks/CU) + A-conversion
//     fused AND pipelined: A(kt+1) fp32-load -> bf16-pack -> ds_write into a
//     DOUBLE-BUFFERED As during the MFMA phase of kt (R8 failed because the
//     same chain sat synchronously in the staging phase). B via DMA from a
//     tiny W_s bf16 pre-convert. LDS 80 KB -> exactly 2 blocks/CU.

#define K_DIM 3136
#define N_DIM 1024
#define C_DIM 256
#define B_DIM 32
#define M_DIM 8192
#define WS_ELEMS (N_DIM * K_DIM)  // 3211264

typedef __attribute__((ext_vector_type(8))) short short8v;  // 8 bf16
typedef __attribute__((ext_vector_type(4))) float f32x4;
typedef __attribute__((ext_vector_type(4))) unsigned int uint4v;

// round-to-nearest-even fp32 -> bf16 (W_s pre-convert)
__device__ __forceinline__ short f2bf(float f) {
  union { float f; unsigned u; } v; v.f = f;
  unsigned r = v.u + 0x7FFFu + ((v.u >> 16) & 1u);
  return (short)(r >> 16);
}

// pack two fp32 -> two bf16 (round-half-up; +-half-ulp, same as RNE scale)
__device__ __forceinline__ unsigned pk2bf(float a, float b) {
  unsigned ua = __float_as_uint(a) + 0x8000u;
  unsigned ub = __float_as_uint(b) + 0x8000u;
  return (ua >> 16) | (ub & 0xFFFF0000u);
}

// 16B-per-lane async global->LDS. LDS dest = wave-uniform base + lane*16.
__device__ __forceinline__ void async16(const void* g, void* l) {
  __builtin_amdgcn_global_load_lds(
      (const __attribute__((address_space(1))) unsigned int*)g,
      (__attribute__((address_space(3))) unsigned int*)l, 16, 0, 0);
}

// fp32 -> bf16 for W_s only (x handled inside gemm), plus bias into out.
#define WSBLK (WS_ELEMS / 2048)  // 1568
__global__ __launch_bounds__(256) void convert_ws_bias(
    const float* __restrict__ Ws, const float* __restrict__ Wb,
    short* __restrict__ dst, float* __restrict__ out) {
  int bid = blockIdx.x;
  if (bid >= WSBLK) {  // bias: 32768 out elems / 256 = 128 blocks
    int i = (bid - WSBLK) * 256 + threadIdx.x;
    out[i] = Wb[i & (N_DIM - 1)];
    return;
  }
  size_t i = (size_t)bid * 2048 + threadIdx.x * 8;
  f32x4 v0 = __builtin_nontemporal_load((const f32x4*)(Ws + i));
  f32x4 v1 = __builtin_nontemporal_load((const f32x4*)(Ws + i) + 1);
  short8v s;
  s[0] = f2bf(v0.x); s[1] = f2bf(v0.y); s[2] = f2bf(v0.z); s[3] = f2bf(v0.w);
  s[4] = f2bf(v1.x); s[5] = f2bf(v1.y); s[6] = f2bf(v1.z); s[7] = f2bf(v1.w);
  *(short8v*)(dst + i) = s;
}

// LDS: rows of 8 chunks (chunk = 8 bf16 = 16 B), unpadded. slot(row, cs)
// holds global chunk cs ^ (row&7); frag reads XOR back -> conflict-free
// (verified R1..R8: SQ_LDS_BANK_CONFLICT = 0). A thread-written (fp32->pack,
// mapping verified correct in R8), B DMA-written.
__global__ __launch_bounds__(512, 4) void gemm_fused(
    const float* __restrict__ x, const short* __restrict__ Bbf,
    const float* __restrict__ Wd, float* __restrict__ out) {
  __shared__ __align__(16) short As[2][256 * 64];  // 2 x 32 KB (dbuf)
  __shared__ __align__(16) short Bs[128 * 64];     // 16 KB

  const int bid = blockIdx.x;
  const int mt = bid & 31;          // bid%8 == mt%8 -> A-tile pinned to XCD
  const int nt = (bid >> 5) & 7;
  const int z = bid >> 8;           // K-split half: 49 = 25 + 24
  const int kt0 = z * 25;
  const int ktn = z ? 24 : 25;

  const int t = threadIdx.x;
  const int lane = t & 63;
  const int wv = t >> 6;            // 0..7
  const int r = lane & 15;
  const int q = lane >> 4;
  const int wm = wv >> 1, wn = wv & 1;  // 4x2 wave grid over 256x128 tile

  // B staging (DMA): lane -> (rr, k8); wave covers rows [wv*16, +16), p=0..1.
  const int rr = lane >> 3;
  const int k8 = (lane & 7) ^ rr;
  const short* Bw = Bbf + (size_t)(nt * 128 + wv * 16 + rr) * K_DIM + k8 * 8 + kt0 * 64;
  char* BsB = (char*)Bs + wv * 2048;

  // A staging (fp32 -> pack -> LDS): lane -> (rr8, c8); w=0..3 covers rows
  // [wv*32 + w*8 + rr8]; slot = c8 ^ rr8 (row&7 == rr8 for every w).
  const int rr8 = lane >> 3;
  const int c8 = lane & 7;
  const int slotA = c8 ^ rr8;
  const float* Ag =
      x + (size_t)(mt * 256 + wv * 32 + rr8) * K_DIM + kt0 * 64 + c8 * 8;
  const int asOff = (wv * 32 + rr8) * 64 + slotA * 8;  // in shorts

  auto stageA = [&](int kt, int buf) {
#pragma unroll
    for (int w = 0; w < 4; ++w) {
      const float* g = Ag + (size_t)w * 8 * K_DIM + kt * 64;
      f32x4 va = *(const f32x4*)g;
      f32x4 vb = *(const f32x4*)(g + 4);
      uint4v u;
      u.x = pk2bf(va.x, va.y);
      u.y = pk2bf(va.z, va.w);
      u.z = pk2bf(vb.x, vb.y);
      u.w = pk2bf(vb.z, vb.w);
      *(uint4v*)(&As[buf][asOff + w * 8 * 64]) = u;
    }
  };

  f32x4 acc[4][4];
#pragma unroll
  for (int i = 0; i < 4; ++i)
#pragma unroll
    for (int j = 0; j < 4; ++j) acc[i][j] = (f32x4)0.0f;

  stageA(0, 0);  // pre-loop prologue; lgkm drained by first barrier pair

  for (int kt = 0; kt < ktn; ++kt) {
    __syncthreads();  // Bs reads of kt-1 done; A ds_writes of kt drained
#pragma unroll
    for (int p = 0; p < 2; ++p)
      async16(Bw + (size_t)p * 8 * K_DIM + kt * 64, BsB + p * 1024);
    __syncthreads();  // B DMA drained (vmcnt(0))

    // pipelined A staging for kt+1: loads have the whole MFMA phase to land;
    // packs/writes co-issue with MFMA (separate pipes), drain at next barrier.
    if (kt + 1 < ktn) stageA(kt + 1, (kt + 1) & 1);

    const short* Ab = As[kt & 1];
#pragma unroll
    for (int ks = 0; ks < 2; ++ks) {
      const int xo = ((ks * 4 + q) ^ (r & 7)) * 16;
      short8v a[4], b[4];
#pragma unroll
      for (int i = 0; i < 4; ++i)
        a[i] = *(const short8v*)((const char*)Ab + (64 * wm + 16 * i + r) * 128 + xo);
#pragma unroll
      for (int j = 0; j < 4; ++j)
        b[j] = *(const short8v*)((const char*)Bs + (64 * wn + 16 * j + r) * 128 + xo);
#pragma unroll
      for (int i = 0; i < 4; ++i)
#pragma unroll
        for (int j = 0; j < 4; ++j)
          acc[i][j] = __builtin_amdgcn_mfma_f32_16x16x32_bf16(a[i], b[j],
                                                              acc[i][j], 0, 0, 0);
    }
  }

  // epilogue: out[mt, n] += sum_c acc * W_d[n, c]; A-tile = image mt, c = row.
  // C/D frag layout: col = lane&15 (n), row = q*4 + reg (c).
#pragma unroll
  for (int j = 0; j < 4; ++j) {
    const int n_g = nt * 128 + 64 * wn + 16 * j + r;
    float p = 0.0f;
#pragma unroll
    for (int i = 0; i < 4; ++i) {
      const int c_l = 64 * wm + 16 * i + 4 * q;
      const float4 wd = *(const float4*)(Wd + (size_t)n_g * C_DIM + c_l);
      p += acc[i][j].x * wd.x + acc[i][j].y * wd.y + acc[i][j].z * wd.z +
           acc[i][j].w * wd.w;
    }
    p += __shfl_xor(p, 16, 64);
    p += __shfl_xor(p, 32, 64);
    if (q == 0) atomicAdd(&out[(size_t)mt * N_DIM + n_g], p);
  }
}

extern "C" void kernel_launch(void* const* d_in, const int* in_sizes, int n_in,
                              void* d_out, int out_size, void* d_ws, size_t ws_size,
                              hipStream_t stream) {
  const float* x = (const float*)d_in[0];
  const float* Ws = (const float*)d_in[1];
  const float* Wd = (const float*)d_in[2];
  const float* Wb = (const float*)d_in[3];
  float* out = (float*)d_out;
  short* wsbf = (short*)d_ws;  // [WS_ELEMS] bf16 W_s only

  convert_ws_bias<<<dim3(WSBLK + 128), dim3(256), 0, stream>>>(Ws, Wb, wsbf, out);
  gemm_fused<<<dim3(32 * 8 * 2), dim3(512), 0, stream>>>(x, wsbf, Wd, out);
}

// Round 11
// 207.743 us; speedup vs baseline: 1.1879x; 1.1879x over previous
//
#include <hip/hip_runtime.h>
#include <stdint.h>

// out[b,n] = sum_{c,hw} x[b,c,hw]*W_s[n,hw]*W_d[n,c] + W_b[n]
// GEMM: A = x (M=8192, K=3136), B = W_s (N=1024, K=3136), fused c-contraction.
// R10: revert to R5 (best: 256x128 tile, 8 waves, BK=64, split-K x2, DMA
//      staging, 2 blocks/CU) after R8/R9 fusion attempts both regressed
//      (shared-vmcnt serialization + spill). Convert: 16 elems/thread.

#define K_DIM 3136
#define N_DIM 1024
#define C_DIM 256
#define B_DIM 32
#define M_DIM 8192
#define X_ELEMS (M_DIM * K_DIM)   // 25690112
#define WS_ELEMS (N_DIM * K_DIM)  // 3211264

typedef __attribute__((ext_vector_type(8))) short short8v;  // 8 bf16
typedef __attribute__((ext_vector_type(4))) float f32x4;

__device__ __forceinline__ short f2bf(float f) {
  union { float f; unsigned u; } v; v.f = f;
  unsigned r = v.u + 0x7FFFu + ((v.u >> 16) & 1u);
  return (short)(r >> 16);
}

// 16B-per-lane async global->LDS. LDS dest = wave-uniform base + lane*16.
__device__ __forceinline__ void async16(const void* g, void* l) {
  __builtin_amdgcn_global_load_lds(
      (const __attribute__((address_space(1))) unsigned int*)g,
      (__attribute__((address_space(3))) unsigned int*)l, 16, 0, 0);
}

// fp32 -> bf16 for x and W_s (16 elems/thread), plus bias into out.
#define XBLK (X_ELEMS / 4096)                 // 6272
#define CVBLK ((X_ELEMS + WS_ELEMS) / 4096)   // 7056
__global__ __launch_bounds__(256) void convert_bf16_bias(
    const float* __restrict__ x, const float* __restrict__ Ws,
    const float* __restrict__ Wb, short* __restrict__ dst,
    float* __restrict__ out) {
  int bid = blockIdx.x;
  if (bid >= CVBLK) {  // bias: 32768 out elems / 256 = 128 blocks
    int i = (bid - CVBLK) * 256 + threadIdx.x;
    out[i] = Wb[i & (N_DIM - 1)];
    return;
  }
  const float* src;
  short* d;
  size_t base;
  if (bid < XBLK) {
    src = x; d = dst; base = (size_t)bid * 4096;
  } else {
    src = Ws; d = dst + X_ELEMS; base = (size_t)(bid - XBLK) * 4096;
  }
#pragma unroll
  for (int h = 0; h < 2; ++h) {
    size_t i = base + threadIdx.x * 8 + h * 2048;
    f32x4 v0 = __builtin_nontemporal_load((const f32x4*)(src + i));
    f32x4 v1 = __builtin_nontemporal_load((const f32x4*)(src + i) + 1);
    short8v s;
    s[0] = f2bf(v0.x); s[1] = f2bf(v0.y); s[2] = f2bf(v0.z); s[3] = f2bf(v0.w);
    s[4] = f2bf(v1.x); s[5] = f2bf(v1.y); s[6] = f2bf(v1.z); s[7] = f2bf(v1.w);
    *(short8v*)(d + i) = s;
  }
}

// LDS: rows of 8 chunks (chunk = 8 bf16 = 16 B), unpadded (DMA dest).
// slot(row, cs) holds global chunk k8 = cs ^ (row&7); frag reads XOR back ->
// conflict-free (verified R1..R8: SQ_LDS_BANK_CONFLICT = 0).
__global__ __launch_bounds__(512, 4) void gemm_fused(
    const short* __restrict__ Abf, const short* __restrict__ Bbf,
    const float* __restrict__ Wd, float* __restrict__ out) {
  __shared__ __align__(16) short As[256 * 64];  // 32 KB
  __shared__ __align__(16) short Bs[128 * 64];  // 16 KB

  const int bid = blockIdx.x;
  const int mt = bid & 31;          // bid%8 == mt%8 -> A-tile pinned to XCD
  const int nt = (bid >> 5) & 7;
  const int z = bid >> 8;           // K-split half: 49 = 25 + 24
  const int kt0 = z * 25;
  const int ktn = z ? 24 : 25;

  const int t = threadIdx.x;
  const int lane = t & 63;
  const int wv = t >> 6;            // 0..7
  const int r = lane & 15;
  const int q = lane >> 4;
  const int wm = wv >> 1, wn = wv & 1;  // 4x2 wave grid over 256x128 tile

  // staging: lane -> (rr, cs); A: wave covers rows [wv*32, +32) via p=0..3,
  // B: rows [wv*16, +16) via p=0..1. Each async16 instr = 8 rows x 8 chunks.
  const int rr = lane >> 3;
  const int k8 = (lane & 7) ^ rr;   // swizzled global chunk for this slot
  const short* Aw = Abf + (size_t)(mt * 256 + wv * 32 + rr) * K_DIM + k8 * 8 + kt0 * 64;
  const short* Bw = Bbf + (size_t)(nt * 128 + wv * 16 + rr) * K_DIM + k8 * 8 + kt0 * 64;
  char* AsB = (char*)As + wv * 4096;
  char* BsB = (char*)Bs + wv * 2048;

  f32x4 acc[4][4];
#pragma unroll
  for (int i = 0; i < 4; ++i)
#pragma unroll
    for (int j = 0; j < 4; ++j) acc[i][j] = (f32x4)0.0f;

  for (int kt = 0; kt < ktn; ++kt) {
    __syncthreads();  // prev iteration's LDS reads done
#pragma unroll
    for (int p = 0; p < 4; ++p)
      async16(Aw + (size_t)p * 8 * K_DIM + kt * 64, AsB + p * 1024);
#pragma unroll
    for (int p = 0; p < 2; ++p)
      async16(Bw + (size_t)p * 8 * K_DIM + kt * 64, BsB + p * 1024);
    __syncthreads();  // vmcnt(0) drain: DMA complete across all waves

#pragma unroll
    for (int ks = 0; ks < 2; ++ks) {
      const int xo = ((ks * 4 + q) ^ (r & 7)) * 16;
      short8v a[4], b[4];
#pragma unroll
      for (int i = 0; i < 4; ++i)
        a[i] = *(const short8v*)((const char*)As + (64 * wm + 16 * i + r) * 128 + xo);
#pragma unroll
      for (int j = 0; j < 4; ++j)
        b[j] = *(const short8v*)((const char*)Bs + (64 * wn + 16 * j + r) * 128 + xo);
#pragma unroll
      for (int i = 0; i < 4; ++i)
#pragma unroll
        for (int j = 0; j < 4; ++j)
          acc[i][j] = __builtin_amdgcn_mfma_f32_16x16x32_bf16(a[i], b[j],
                                                              acc[i][j], 0, 0, 0);
    }
  }

  // epilogue: out[mt, n] += sum_c acc * W_d[n, c]; A-tile = image mt, c = row.
  // C/D frag layout: col = lane&15 (n), row = q*4 + reg (c).
#pragma unroll
  for (int j = 0; j < 4; ++j) {
    const int n_g = nt * 128 + 64 * wn + 16 * j + r;
    float p = 0.0f;
#pragma unroll
    for (int i = 0; i < 4; ++i) {
      const int c_l = 64 * wm + 16 * i + 4 * q;
      const float4 wd = *(const float4*)(Wd + (size_t)n_g * C_DIM + c_l);
      p += acc[i][j].x * wd.x + acc[i][j].y * wd.y + acc[i][j].z * wd.z +
           acc[i][j].w * wd.w;
    }
    p += __shfl_xor(p, 16, 64);
    p += __shfl_xor(p, 32, 64);
    if (q == 0) atomicAdd(&out[(size_t)mt * N_DIM + n_g], p);
  }
}

extern "C" void kernel_launch(void* const* d_in, const int* in_sizes, int n_in,
                              void* d_out, int out_size, void* d_ws, size_t ws_size,
                              hipStream_t stream) {
  const float* x = (const float*)d_in[0];
  const float* Ws = (const float*)d_in[1];
  const float* Wd = (const float*)d_in[2];
  const float* Wb = (const float*)d_in[3];
  float* out = (float*)d_out;
  short* xbf = (short*)d_ws;  // [X_ELEMS] bf16 x, then [WS_ELEMS] bf16 W_s

  convert_bf16_bias<<<dim3(CVBLK + 128), dim3(256), 0, stream>>>(x, Ws, Wb, xbf, out);
  gemm_fused<<<dim3(32 * 8 * 2), dim3(512), 0, stream>>>(xbf, xbf + X_ELEMS, Wd, out);
}